// Round 1
// baseline (87.295 us; speedup 1.0000x reference)
//
#include <hip/hip_runtime.h>

#define BB 32
#define SS 22
#define NN 2048
#define HH 8
#define DKK 8
#define PP 6

__global__ __launch_bounds__(256, 1) void mha_kernel(
    const float* __restrict__ q, const float* __restrict__ k, const float* __restrict__ v,
    const int* __restrict__ mask,
    const float* __restrict__ Wq, const float* __restrict__ bq,
    const float* __restrict__ Wk, const float* __restrict__ bk,
    const float* __restrict__ Wv, const float* __restrict__ bv,
    const float* __restrict__ Wc, const float* __restrict__ bc,
    const float* __restrict__ Wf, const float* __restrict__ bf,
    float* __restrict__ out)
{
    __shared__ float Ms[HH][9];
    __shared__ float Us[HH][3];
    __shared__ unsigned mb[SS];

    const int tid = threadIdx.x;
    // --- per-block precompute of the collapsed weight forms ---
    if (tid < 72) {
        int h = tid / 9, ij = tid - h * 9, i = ij / 3, j = ij - i * 3;
        float acc = 0.f;
        for (int d = 0; d < DKK; ++d) {
            int c = h * DKK + d;
            float a  = (i == 0) ? Wq[2 * c] : (i == 1) ? Wq[2 * c + 1] : bq[c];
            float bbv = (j == 0) ? Wk[2 * c] : (j == 1) ? Wk[2 * c + 1] : bk[c];
            acc = fmaf(a, bbv, acc);
        }
        // fold 1/DK^2 attention scale and log2(e) (for exp2) into M
        Ms[h][ij] = acc * (1.4426950408889634f / 64.f);
    } else if (tid < 96) {
        int r = tid - 72, h = r / 3, j = r - h * 3;
        float acc = 0.f;
        for (int d = 0; d < DKK; ++d) {
            int c = h * DKK + d;
            float a = (j == 0) ? Wv[2 * c] : (j == 1) ? Wv[2 * c + 1] : bv[c];
            acc = fmaf(a, Wc[c], acc);
        }
        Us[h][j] = acc;
    } else if (tid < 96 + SS) {
        int s = tid - 96;
        unsigned bitsv = 0;
        for (int t = 0; t < SS; ++t)
            if (mask[s * SS + t] != 0) bitsv |= (1u << t);
        mb[s] = bitsv;
    }
    __syncthreads();

    const int gid = blockIdx.x * 256 + tid;
    const int b = gid >> 11;          // NN = 2048
    const int n = gid & (NN - 1);

    const float2* qp = (const float2*)q;
    const float2* kp = (const float2*)k;
    const float2* vp = (const float2*)v;

    float2 qx[SS], kx[SS], vx[SS];
#pragma unroll
    for (int s = 0; s < SS; ++s) {
        int idx = (b * SS + s) * NN + n;
        qx[s] = qp[idx];
        kx[s] = kp[idx];
        vx[s] = vp[idx];
    }

    const float bc0 = bc[0];
    float c_acc[SS];
#pragma unroll
    for (int s = 0; s < SS; ++s) c_acc[s] = bc0;

#pragma unroll 1
    for (int h = 0; h < HH; ++h) {
        const float m00 = Ms[h][0], m01 = Ms[h][1], m02 = Ms[h][2];
        const float m10 = Ms[h][3], m11 = Ms[h][4], m12 = Ms[h][5];
        const float m20 = Ms[h][6], m21 = Ms[h][7], m22 = Ms[h][8];
        const float u0 = Us[h][0], u1 = Us[h][1], u2 = Us[h][2];

        float w[SS];
        float wsum = 0.f;
#pragma unroll
        for (int t = 0; t < SS; ++t) {
            w[t] = fmaf(vx[t].x, u0, fmaf(vx[t].y, u1, u2));
            wsum += w[t];
        }

#pragma unroll
        for (int s = 0; s < SS; ++s) {
            const float g0 = fmaf(qx[s].x, m00, fmaf(qx[s].y, m10, m20));
            const float g1 = fmaf(qx[s].x, m01, fmaf(qx[s].y, m11, m21));
            const float g2 = fmaf(qx[s].x, m02, fmaf(qx[s].y, m12, m22));
            const unsigned bits = (unsigned)__builtin_amdgcn_readfirstlane((int)mb[s]);
            if (bits == 0) {
                // fully-masked row: reference softmax degenerates to uniform 1/S
                c_acc[s] = fmaf(wsum, (1.f / (float)SS), c_acc[s]);
            } else {
                float sume = 0.f, dot = 0.f;
#pragma unroll
                for (int t = 0; t < SS; ++t) {
                    if (bits & (1u << t)) {   // wave-uniform branch (bits in SGPR)
                        float att = fmaf(g0, kx[t].x, fmaf(g1, kx[t].y, g2));
                        float e = __builtin_amdgcn_exp2f(att);
                        sume += e;
                        dot = fmaf(e, w[t], dot);
                    }
                    // masked entries: exp(-2^15 - m) == 0.0f exactly in the reference
                }
                c_acc[s] = fmaf(dot, __builtin_amdgcn_rcpf(sume), c_acc[s]);
            }
        }
    }

    // final: out[b,p,n] = bf[p] + sum_s c_acc[s] * Wf[p,s]   (uniform weights -> s_loads)
#pragma unroll
    for (int p = 0; p < PP; ++p) {
        float o = bf[p];
#pragma unroll
        for (int s = 0; s < SS; ++s) o = fmaf(c_acc[s], Wf[p * SS + s], o);
        out[(b * PP + p) * NN + n] = o;
    }
}

extern "C" void kernel_launch(void* const* d_in, const int* in_sizes, int n_in,
                              void* d_out, int out_size, void* d_ws, size_t ws_size,
                              hipStream_t stream) {
    const float* q  = (const float*)d_in[0];
    const float* k  = (const float*)d_in[1];
    const float* v  = (const float*)d_in[2];
    const int* mask = (const int*)d_in[3];
    const float* Wq = (const float*)d_in[4];
    const float* bq = (const float*)d_in[5];
    const float* Wk = (const float*)d_in[6];
    const float* bk = (const float*)d_in[7];
    const float* Wv = (const float*)d_in[8];
    const float* bv = (const float*)d_in[9];
    const float* Wc = (const float*)d_in[10];
    const float* bc = (const float*)d_in[11];
    const float* Wf = (const float*)d_in[12];
    const float* bf = (const float*)d_in[13];
    float* out = (float*)d_out;

    dim3 grid(BB * NN / 256), block(256);
    hipLaunchKernelGGL(mha_kernel, grid, block, 0, stream,
                       q, k, v, mask, Wq, bq, Wk, bk, Wv, bv, Wc, bc, Wf, bf, out);
}

// Round 2
// 57.591 us; speedup vs baseline: 1.5158x; 1.5158x over previous
//
#include <hip/hip_runtime.h>

#define BB 32
#define SS 22
#define NN 2048
#define HH 8
#define DKK 8
#define PP 6

__global__ __launch_bounds__(256, 4) void mha_kernel(
    const float* __restrict__ q, const float* __restrict__ k, const float* __restrict__ v,
    const int* __restrict__ mask,
    const float* __restrict__ Wq, const float* __restrict__ bq,
    const float* __restrict__ Wk, const float* __restrict__ bk,
    const float* __restrict__ Wv, const float* __restrict__ bv,
    const float* __restrict__ Wc, const float* __restrict__ bc,
    const float* __restrict__ Wf, const float* __restrict__ bf,
    float* __restrict__ out)
{
    __shared__ float Ms[HH][9];
    __shared__ float Us[HH][3];
    __shared__ unsigned mb[SS];

    const int tid = threadIdx.x;
    // --- per-block precompute of the collapsed weight forms ---
    if (tid < 72) {
        int hh = tid / 9, ij = tid - hh * 9, i = ij / 3, j = ij - i * 3;
        float acc = 0.f;
        for (int d = 0; d < DKK; ++d) {
            int c = hh * DKK + d;
            float a  = (i == 0) ? Wq[2 * c] : (i == 1) ? Wq[2 * c + 1] : bq[c];
            float bb = (j == 0) ? Wk[2 * c] : (j == 1) ? Wk[2 * c + 1] : bk[c];
            acc = fmaf(a, bb, acc);
        }
        // fold 1/DK^2 attention scale and log2(e) (for exp2) into M
        Ms[hh][ij] = acc * (1.4426950408889634f / 64.f);
    } else if (tid < 96) {
        int r = tid - 72, hh = r / 3, j = r - hh * 3;
        float acc = 0.f;
        for (int d = 0; d < DKK; ++d) {
            int c = hh * DKK + d;
            float a = (j == 0) ? Wv[2 * c] : (j == 1) ? Wv[2 * c + 1] : bv[c];
            acc = fmaf(a, Wc[c], acc);
        }
        Us[hh][j] = acc;
    } else if (tid < 96 + SS) {
        int s = tid - 96;
        unsigned bitsv = 0;
        for (int t = 0; t < SS; ++t)
            if (mask[s * SS + t] != 0) bitsv |= (1u << t);
        mb[s] = bitsv;
    }
    __syncthreads();

    // thread = (b, n, h); h fastest so the 8 head-threads of a (b,n) pair
    // occupy 8 consecutive lanes -> shuffle-reduce stays in-wave.
    const int gid  = blockIdx.x * 256 + tid;
    const int h    = gid & (HH - 1);
    const int pair = gid >> 3;
    const int b    = pair >> 11;          // NN = 2048
    const int n    = pair & (NN - 1);

    const float2* qp = (const float2*)q;
    const float2* kp = (const float2*)k;
    const float2* vp = (const float2*)v;
    const int base = (b * SS) * NN + n;   // + s*NN per row

    const float m00 = Ms[h][0], m01 = Ms[h][1], m02 = Ms[h][2];
    const float m10 = Ms[h][3], m11 = Ms[h][4], m12 = Ms[h][5];
    const float m20 = Ms[h][6], m21 = Ms[h][7], m22 = Ms[h][8];
    const float u0 = Us[h][0], u1 = Us[h][1], u2 = Us[h][2];

    // K rows stay resident; V rows are consumed into w on load.
    float2 kx[SS];
    float  w[SS];
    float wsA = 0.f, wsB = 0.f;
#pragma unroll
    for (int t = 0; t < SS; ++t) {
        kx[t] = kp[base + t * NN];
        float2 vv = vp[base + t * NN];
        w[t] = fmaf(vv.x, u0, fmaf(vv.y, u1, u2));
        if (t & 1) wsB += w[t]; else wsA += w[t];
    }
    const float wsum = wsA + wsB;

    float c_part[SS];
#pragma unroll
    for (int s = 0; s < SS; ++s) {
        const unsigned bits = (unsigned)__builtin_amdgcn_readfirstlane((int)mb[s]);
        const float2 qq = qp[base + s * NN];   // streamed, not kept resident
        if (bits == 0) {
            // fully-masked row: reference softmax degenerates to uniform 1/S
            c_part[s] = wsum * (1.f / (float)SS);
        } else {
            const float g0 = fmaf(qq.x, m00, fmaf(qq.y, m10, m20));
            const float g1 = fmaf(qq.x, m01, fmaf(qq.y, m11, m21));
            const float g2 = fmaf(qq.x, m02, fmaf(qq.y, m12, m22));
            float sA = 0.f, sB = 0.f, dA = 0.f, dB = 0.f;
#pragma unroll
            for (int t = 0; t < SS; ++t) {
                if (bits & (1u << t)) {   // wave-uniform branch (bits in SGPR)
                    float att = fmaf(g0, kx[t].x, fmaf(g1, kx[t].y, g2));
                    float e = __builtin_amdgcn_exp2f(att);
                    if (t & 1) { sB += e; dB = fmaf(e, w[t], dB); }
                    else       { sA += e; dA = fmaf(e, w[t], dA); }
                }
                // masked entries: exp(-2^15 - m) == 0.0f exactly in the reference
            }
            c_part[s] = (dA + dB) * __builtin_amdgcn_rcpf(sA + sB);
        }
    }

    // merge heads: butterfly sum across the 8 h-lanes (masks 1,2,4)
#pragma unroll
    for (int s = 0; s < SS; ++s) {
        float cv = c_part[s];
        cv += __shfl_xor(cv, 1);
        cv += __shfl_xor(cv, 2);
        cv += __shfl_xor(cv, 4);
        c_part[s] = cv;          // all 8 lanes now hold the head-summed value
    }

    // epilogue parallelized over p = h (6 of 8 lanes active)
    if (h < PP) {
        const int p = h;
        const float bc0 = bc[0];
        float o = bf[p];
#pragma unroll
        for (int s = 0; s < SS; ++s)
            o = fmaf(c_part[s] + bc0, Wf[p * SS + s], o);
        out[(b * PP + p) * NN + n] = o;
    }
}

extern "C" void kernel_launch(void* const* d_in, const int* in_sizes, int n_in,
                              void* d_out, int out_size, void* d_ws, size_t ws_size,
                              hipStream_t stream) {
    const float* q  = (const float*)d_in[0];
    const float* k  = (const float*)d_in[1];
    const float* v  = (const float*)d_in[2];
    const int* mask = (const int*)d_in[3];
    const float* Wq = (const float*)d_in[4];
    const float* bq = (const float*)d_in[5];
    const float* Wk = (const float*)d_in[6];
    const float* bk = (const float*)d_in[7];
    const float* Wv = (const float*)d_in[8];
    const float* bv = (const float*)d_in[9];
    const float* Wc = (const float*)d_in[10];
    const float* bc = (const float*)d_in[11];
    const float* Wf = (const float*)d_in[12];
    const float* bf = (const float*)d_in[13];
    float* out = (float*)d_out;

    dim3 grid(BB * NN * HH / 256), block(256);
    hipLaunchKernelGGL(mha_kernel, grid, block, 0, stream,
                       q, k, v, mask, Wq, bq, Wk, bk, Wv, bv, Wc, bc, Wf, bf, out);
}